// Round 8
// baseline (218.338 us; speedup 1.0000x reference)
//
#include <hip/hip_runtime.h>

#define N_USER 50000
#define N_ITEM 50000
#define N_EDGE 800000
#define D 128
#define NTOT   100000          // combined dst space: [0,50K)=items, [50K,100K)=users
#define NE2    1600000         // both directions' edges
#define BKT_SH 9               // 512 dsts per bucket
#define NBKT   196             // ceil(NTOT / 512)
#define CAP    12288           // LDS csr staging cap (bucket mean 8192, sigma ~90)

typedef __attribute__((ext_vector_type(8))) short     bf16x8;
typedef __attribute__((ext_vector_type(4))) float     f32x4;
typedef __attribute__((ext_vector_type(4))) unsigned short ushortx4;
typedef __attribute__((ext_vector_type(8))) unsigned short ushortx8;

__device__ __forceinline__ unsigned short f2bf(float f) {
    unsigned int u = __float_as_uint(f);
    unsigned int r = (u + 0x7fffu + ((u >> 16) & 1u)) >> 16;   // RNE
    return (unsigned short)r;
}
__device__ __forceinline__ float bf2f(unsigned short b) {
    return __uint_as_float(((unsigned int)b) << 16);
}

// ---------------------------------------------------------------------------
// PREP mega-kernel (block-range roles):
//  [0, 12500)         pack features -> compact bf16 tables T_user/T_item
//  [12500, 12891)     bucket-count: LDS-binned count of 1.6M edges -> gcnt[196]
//  [12891, 12923)     pack W frags (2 x 4096 ids)
// ---------------------------------------------------------------------------
#define PACKA_BLOCKS 12500
#define CNT_BLOCKS   391       // ceil(NE2 / 4096)
#define PACKW_BLOCKS 32

__global__ __launch_bounds__(256) void prep2_kernel(
    const float* __restrict__ user_emb, const int* __restrict__ user_ids,
    const float* __restrict__ item_x,
    const int* __restrict__ edge_ui, const int* __restrict__ edge_iu,
    const float* __restrict__ Wl_ui, const float* __restrict__ Wr_ui,
    const float* __restrict__ Wl_iu, const float* __restrict__ Wr_iu,
    unsigned short* T_user, unsigned short* T_item,
    int* gcnt, unsigned short* WfragUI, unsigned short* WfragIU)
{
    __shared__ int bcnt[NBKT];
    const int b = blockIdx.x;
    const int tid = threadIdx.x;

    if (b < PACKA_BLOCKS) {
        int gid = b * 256 + tid;
        int row = gid >> 5;
        int c = (gid & 31) << 2;
        const float* src;
        unsigned short* dst;
        if (row < N_USER) {
            src = user_emb + (size_t)user_ids[row] * D;
            dst = T_user + (size_t)row * 128;
        } else {
            int r = row - N_USER;
            src = item_x + (size_t)r * D;
            dst = T_item + (size_t)r * 128;
        }
        const float4 v = *reinterpret_cast<const float4*>(src + c);
        ushortx4 o;
        o.x = f2bf(v.x); o.y = f2bf(v.y); o.z = f2bf(v.z); o.w = f2bf(v.w);
        *reinterpret_cast<ushortx4*>(dst + c) = o;
    } else if (b < PACKA_BLOCKS + CNT_BLOCKS) {
        for (int i = tid; i < NBKT; i += 256) bcnt[i] = 0;
        __syncthreads();
        int e0 = (b - PACKA_BLOCKS) * 4096;
#pragma unroll
        for (int j = 0; j < 16; ++j) {
            int e = e0 + j * 256 + tid;
            if (e < NE2) {
                int d = (e < N_EDGE) ? edge_ui[N_EDGE + e]
                                     : (N_ITEM + edge_iu[N_EDGE + (e - N_EDGE)]);
                atomicAdd(&bcnt[d >> BKT_SH], 1);
            }
        }
        __syncthreads();
        for (int i = tid; i < NBKT; i += 256)
            if (bcnt[i]) atomicAdd(&gcnt[i], bcnt[i]);
    } else {
        int id = (b - PACKA_BLOCKS - CNT_BLOCKS) * 256 + tid;   // [0, 8192)
        const float *Wl, *Wr;
        unsigned short* Wf;
        if (id < 4096) { Wl = Wl_ui; Wr = Wr_ui; Wf = WfragUI; }
        else { id -= 4096; Wl = Wl_iu; Wr = Wr_iu; Wf = WfragIU; }
        int lane = id & 63;
        int c    = (id >> 6) & 7;
        int ks   = id >> 9;
        int col  = c * 16 + (lane & 15);
        int k0   = ks * 32 + (lane >> 4) * 8;
        ushortx8 o;
#pragma unroll
        for (int i = 0; i < 8; ++i) {
            int k = k0 + i;
            float f = (k < D) ? Wl[(size_t)k * D + col] : Wr[(size_t)(k - D) * D + col];
            o[i] = f2bf(f);
        }
        *reinterpret_cast<ushortx8*>(Wf + (size_t)id * 8) = o;
    }
}

// ---------------------------------------------------------------------------
// Scan 196 bucket counts -> bucket bases; init bucket cursors.
// ---------------------------------------------------------------------------
__global__ __launch_bounds__(256) void bucketscan_kernel(
    const int* __restrict__ gcnt, int* __restrict__ bbase, int* __restrict__ bcur)
{
    __shared__ int s[256];
    int tid = threadIdx.x;
    int v = (tid < NBKT) ? gcnt[tid] : 0;
    s[tid] = v;
    __syncthreads();
    for (int d = 1; d < 256; d <<= 1) {
        int t = (tid >= d) ? s[tid - d] : 0;
        __syncthreads();
        s[tid] += t;
        __syncthreads();
    }
    if (tid < NBKT) {
        int base = s[tid] - v;     // exclusive
        bbase[tid] = base;
        bcur[tid]  = base;
    }
    if (tid == NBKT - 1) bbase[NBKT] = s[tid];
}

// ---------------------------------------------------------------------------
// Scatter records into bucket-segmented array. Record = src16 | dstlow9<<16.
// ---------------------------------------------------------------------------
#define B2_BLOCKS 98   // ceil(NE2 / 16384)

__global__ __launch_bounds__(1024) void scatter_records_kernel(
    const int* __restrict__ edge_ui, const int* __restrict__ edge_iu,
    int* __restrict__ bcur, unsigned int* __restrict__ records)
{
    __shared__ int bcnt[NBKT];
    __shared__ int bpos[NBKT];
    const int tid = threadIdx.x;
    for (int i = tid; i < NBKT; i += 1024) bcnt[i] = 0;
    __syncthreads();

    const int e0 = blockIdx.x * 16384;
    unsigned int rec[16];
    int bkt[16];
#pragma unroll
    for (int j = 0; j < 16; ++j) {
        int e = e0 + j * 1024 + tid;
        bkt[j] = -1;
        rec[j] = 0;
        if (e < NE2) {
            int s, d;
            if (e < N_EDGE) { s = edge_ui[e]; d = edge_ui[N_EDGE + e]; }
            else { int f = e - N_EDGE; s = edge_iu[f]; d = N_ITEM + edge_iu[N_EDGE + f]; }
            bkt[j] = d >> BKT_SH;
            rec[j] = (unsigned int)s | ((unsigned int)(d & 511) << 16);
            atomicAdd(&bcnt[bkt[j]], 1);
        }
    }
    __syncthreads();
    for (int i = tid; i < NBKT; i += 1024) {
        int c = bcnt[i];
        bpos[i] = c ? atomicAdd(&bcur[i], c) : 0;
    }
    __syncthreads();
#pragma unroll
    for (int j = 0; j < 16; ++j) {
        if (bkt[j] >= 0) {
            int p = atomicAdd(&bpos[bkt[j]], 1);
            records[p] = rec[j];
        }
    }
}

// ---------------------------------------------------------------------------
// Per-bucket CSR build: LDS counting-sort by dst within the bucket; emits off[].
// ---------------------------------------------------------------------------
__global__ __launch_bounds__(1024) void csr_build_kernel(
    const unsigned int* __restrict__ records, const int* __restrict__ bbase,
    unsigned short* __restrict__ csr, int* __restrict__ off)
{
    __shared__ int dcnt[512];
    __shared__ int sa[512], sb[512];
    __shared__ int dcur[512];
    __shared__ unsigned short stage[CAP];

    const int b    = blockIdx.x;
    const int tid  = threadIdx.x;
    const int base = bbase[b];
    const int nb   = bbase[b + 1] - base;

    if (tid < 512) dcnt[tid] = 0;
    __syncthreads();

    for (int i = tid; i < nb; i += 1024)
        atomicAdd(&dcnt[records[base + i] >> 16], 1);
    __syncthreads();

    int* pa = sa; int* pb = sb;
    if (tid < 512) pa[tid] = dcnt[tid];
    __syncthreads();
    for (int d = 1; d < 512; d <<= 1) {
        if (tid < 512) pb[tid] = pa[tid] + ((tid >= d) ? pa[tid - d] : 0);
        __syncthreads();
        int* t = pa; pa = pb; pb = t;
    }
    if (tid < 512) {
        int excl = pa[tid] - dcnt[tid];
        dcur[tid] = excl;
        int dst = b * 512 + tid;
        if (dst < NTOT) off[dst] = base + excl;
    }
    if (b == NBKT - 1 && tid == 0) off[NTOT] = NE2;
    __syncthreads();

    if (nb <= CAP) {
        for (int i = tid; i < nb; i += 1024) {
            unsigned int r = records[base + i];
            int p = atomicAdd(&dcur[r >> 16], 1);
            stage[p] = (unsigned short)r;
        }
        __syncthreads();
        for (int i = tid; i < nb; i += 1024) csr[base + i] = stage[i];
    } else {
        for (int i = tid; i < nb; i += 1024) {
            unsigned int r = records[base + i];
            int p = atomicAdd(&dcur[r >> 16], 1);
            csr[base + p] = (unsigned short)r;
        }
    }
}

// ---------------------------------------------------------------------------
// FUSED aggregate + MFMA finish.
// Tg = gather table (neighbor/source features, opposite node type)
// Ts = self table   (destination node type's own features, the @Wr operand)
// Block = 64 output rows of one side; 4 waves. Wave w:
//   phase 1: aggregate rows [rowBase+16w, +16) from Tg -> LDS head tile
//   phase 2: MFMA out[64][128] = [head|Ts row] @ Wfrag + bias -> d_out (fp32)
// ---------------------------------------------------------------------------
#define NB_FIN 782   // ceil(50000/64)

__global__ __launch_bounds__(256) void aggfin_kernel(
    const unsigned short* __restrict__ T_user, const unsigned short* __restrict__ T_item,
    const int* __restrict__ off, const unsigned short* __restrict__ csr,
    const unsigned short* __restrict__ WfragUI, const unsigned short* __restrict__ WfragIU,
    const float* __restrict__ b_ui, const float* __restrict__ b_iu,
    float* out_item, float* out_user)
{
    __shared__ unsigned short hd[64][136];   // head tile, padded stride

    const int b = blockIdx.x;
    const unsigned short *Tg, *Ts, *Wfrag;
    const float* bias;
    float* outp;
    int rowBase, dstOfs;
    if (b < NB_FIN) {
        // item side: aggregate USER features, self = ITEM features
        Tg = T_user; Ts = T_item; Wfrag = WfragUI; bias = b_ui;
        outp = out_item; rowBase = b * 64; dstOfs = 0;
    } else {
        // user side: aggregate ITEM features, self = USER features
        Tg = T_item; Ts = T_user; Wfrag = WfragIU; bias = b_iu;
        outp = out_user; rowBase = (b - NB_FIN) * 64; dstOfs = N_ITEM;
    }

    const int tid  = threadIdx.x;
    const int wave = tid >> 6;
    const int lane = tid & 63;
    const int half = lane >> 5;
    const int hl   = lane & 31;

    // ---- phase 1: aggregation (gather from Tg) ----
    for (int rr = 0; rr < 16; ++rr) {
        const int lrow = wave * 16 + rr;
        const int row  = rowBase + lrow;
        float a0 = 0.f, a1 = 0.f, a2 = 0.f, a3 = 0.f;
        int deg = 0;
        if (row < 50000) {
            const int dr = dstOfs + row;
            const int o0 = off[dr], o1 = off[dr + 1];
            deg = o1 - o0;
            for (int base = o0; base < o1; base += 64) {
                int navail = o1 - base; if (navail > 64) navail = 64;
                int li = (lane < navail) ? lane : (navail - 1);
                int csrv = csr[base + li];            // coalesced u16 chunk
                int fullp = navail >> 1;
#pragma unroll 2
                for (int it = 0; it < fullp; ++it) {
                    int src = __shfl(csrv, 2 * it + half);
                    uint2 w = *reinterpret_cast<const uint2*>(Tg + (size_t)src * 128 + hl * 4);
                    a0 += bf2f((unsigned short)w.x); a1 += bf2f((unsigned short)(w.x >> 16));
                    a2 += bf2f((unsigned short)w.y); a3 += bf2f((unsigned short)(w.y >> 16));
                }
                if (navail & 1) {
                    int src = __shfl(csrv, navail - 1);
                    if (half == 0) {
                        uint2 w = *reinterpret_cast<const uint2*>(Tg + (size_t)src * 128 + hl * 4);
                        a0 += bf2f((unsigned short)w.x); a1 += bf2f((unsigned short)(w.x >> 16));
                        a2 += bf2f((unsigned short)w.y); a3 += bf2f((unsigned short)(w.y >> 16));
                    }
                }
            }
        }
        a0 += __shfl_xor(a0, 32); a1 += __shfl_xor(a1, 32);
        a2 += __shfl_xor(a2, 32); a3 += __shfl_xor(a3, 32);
        float sc = (deg > 0) ? 1.0f / (float)deg : 0.0f;
        if (half == 0) {
            unsigned int p0 = (unsigned int)f2bf(a0 * sc) | ((unsigned int)f2bf(a1 * sc) << 16);
            unsigned int p1 = (unsigned int)f2bf(a2 * sc) | ((unsigned int)f2bf(a3 * sc) << 16);
            *reinterpret_cast<uint2*>(&hd[lrow][hl * 4]) = make_uint2(p0, p1);
        }
    }
    __syncthreads();

    // ---- phase 2: MFMA ----
    const int kg = lane >> 4;
    const int arow = rowBase + wave * 16 + (lane & 15);
    const int arow_c = (arow < 50000) ? arow : 49999;
    const unsigned short* tail_ptr = Ts + (size_t)arow_c * 128 + kg * 8;   // SELF features
    const unsigned short* hrow = &hd[wave * 16 + (lane & 15)][kg * 8];

    f32x4 acc[8];
#pragma unroll
    for (int c = 0; c < 8; ++c) acc[c] = (f32x4){0.f, 0.f, 0.f, 0.f};

#pragma unroll
    for (int ks = 0; ks < 8; ++ks) {
        bf16x8 a;
        if (ks < 4) a = *reinterpret_cast<const bf16x8*>(hrow + ks * 32);           // agg (Wl)
        else        a = *reinterpret_cast<const bf16x8*>(tail_ptr + (ks - 4) * 32); // self (Wr)
        const unsigned short* bptr = Wfrag + ((size_t)(ks * 8) * 64 + lane) * 8;
#pragma unroll
        for (int c = 0; c < 8; ++c) {
            bf16x8 bb = *reinterpret_cast<const bf16x8*>(bptr + (size_t)c * 512);
            acc[c] = __builtin_amdgcn_mfma_f32_16x16x32_bf16(a, bb, acc[c], 0, 0, 0);
        }
    }

    const int orow0 = rowBase + wave * 16 + kg * 4;
    const int ocol  = lane & 15;
#pragma unroll
    for (int c = 0; c < 8; ++c) {
        float bv = bias[c * 16 + ocol];
#pragma unroll
        for (int r = 0; r < 4; ++r) {
            int row = orow0 + r;
            if (row < 50000) outp[(size_t)row * 128 + c * 16 + ocol] = acc[c][r] + bv;
        }
    }
}

// ---------------------------------------------------------------------------
extern "C" void kernel_launch(void* const* d_in, const int* in_sizes, int n_in,
                              void* d_out, int out_size, void* d_ws, size_t ws_size,
                              hipStream_t stream) {
    const int*   user_ids = (const int*)d_in[0];
    const float* item_x   = (const float*)d_in[1];
    const int*   edge_ui  = (const int*)d_in[2];
    const int*   edge_iu  = (const int*)d_in[3];
    const float* user_emb = (const float*)d_in[4];
    const float* W_l_ui   = (const float*)d_in[5];
    const float* W_r_ui   = (const float*)d_in[6];
    const float* b_ui     = (const float*)d_in[7];
    const float* W_l_iu   = (const float*)d_in[8];
    const float* W_r_iu   = (const float*)d_in[9];
    const float* b_iu     = (const float*)d_in[10];

    float* out_user = (float*)d_out;
    float* out_item = out_user + (size_t)N_USER * D;

    // Workspace (16B-aligned blocks first)
    unsigned short* WfragUI = (unsigned short*)d_ws;            // 32768 u16
    unsigned short* WfragIU = WfragUI + 32768;                  // 32768 u16
    unsigned short* T_user  = WfragIU + 32768;                  // 50000*128 u16 (12.8MB)
    unsigned short* T_item  = T_user + (size_t)N_USER * 128;    // 12.8MB
    unsigned int*   records = (unsigned int*)(T_item + (size_t)N_ITEM * 128);  // NE2 (6.4MB)
    unsigned short* csr     = (unsigned short*)(records + NE2); // NE2 (3.2MB)
    int* gcnt  = (int*)(csr + NE2);                             // NBKT
    int* bbase = gcnt + NBKT;                                   // NBKT+1
    int* bcur  = bbase + NBKT + 1;                              // NBKT
    int* off   = bcur + NBKT;                                   // NTOT+1

    hipMemsetAsync(gcnt, 0, NBKT * sizeof(int), stream);

    prep2_kernel<<<PACKA_BLOCKS + CNT_BLOCKS + PACKW_BLOCKS, 256, 0, stream>>>(
        user_emb, user_ids, item_x, edge_ui, edge_iu,
        W_l_ui, W_r_ui, W_l_iu, W_r_iu,
        T_user, T_item, gcnt, WfragUI, WfragIU);

    bucketscan_kernel<<<1, 256, 0, stream>>>(gcnt, bbase, bcur);
    scatter_records_kernel<<<B2_BLOCKS, 1024, 0, stream>>>(edge_ui, edge_iu, bcur, records);
    csr_build_kernel<<<NBKT, 1024, 0, stream>>>(records, bbase, csr, off);

    aggfin_kernel<<<2 * NB_FIN, 256, 0, stream>>>(
        T_user, T_item, off, csr, WfragUI, WfragIU, b_ui, b_iu, out_item, out_user);
}

// Round 9
// 163.023 us; speedup vs baseline: 1.3393x; 1.3393x over previous
//
#include <hip/hip_runtime.h>

#define N_USER 50000
#define N_ITEM 50000
#define N_EDGE 800000
#define D 128
#define NTOT   100000          // combined dst space: [0,50K)=items, [50K,100K)=users
#define NE2    1600000         // both directions' edges
#define BKT_SH 9               // 512 dsts per bucket
#define NBKT   196             // ceil(NTOT / 512)
#define CAP    12288           // LDS csr staging cap (bucket mean 8192, sigma ~90)

typedef __attribute__((ext_vector_type(8))) short     bf16x8;
typedef __attribute__((ext_vector_type(4))) float     f32x4;
typedef __attribute__((ext_vector_type(4))) unsigned short ushortx4;
typedef __attribute__((ext_vector_type(8))) unsigned short ushortx8;

__device__ __forceinline__ unsigned short f2bf(float f) {
    unsigned int u = __float_as_uint(f);
    unsigned int r = (u + 0x7fffu + ((u >> 16) & 1u)) >> 16;   // RNE
    return (unsigned short)r;
}
__device__ __forceinline__ float bf2f(unsigned short b) {
    return __uint_as_float(((unsigned int)b) << 16);
}

// ---------------------------------------------------------------------------
// PREP mega-kernel (block-range roles):
//  [0, 12500)         pack features -> compact bf16 tables T_user/T_item
//  [12500, 12891)     bucket-count: LDS-binned count of 1.6M edges -> gcnt[196]
//  [12891, 12923)     pack W frags (2 x 4096 ids)
// ---------------------------------------------------------------------------
#define PACKA_BLOCKS 12500
#define CNT_BLOCKS   391       // ceil(NE2 / 4096)
#define PACKW_BLOCKS 32

__global__ __launch_bounds__(256) void prep2_kernel(
    const float* __restrict__ user_emb, const int* __restrict__ user_ids,
    const float* __restrict__ item_x,
    const int* __restrict__ edge_ui, const int* __restrict__ edge_iu,
    const float* __restrict__ Wl_ui, const float* __restrict__ Wr_ui,
    const float* __restrict__ Wl_iu, const float* __restrict__ Wr_iu,
    unsigned short* T_user, unsigned short* T_item,
    int* gcnt, unsigned short* WfragUI, unsigned short* WfragIU)
{
    __shared__ int bcnt[NBKT];
    const int b = blockIdx.x;
    const int tid = threadIdx.x;

    if (b < PACKA_BLOCKS) {
        int gid = b * 256 + tid;
        int row = gid >> 5;
        int c = (gid & 31) << 2;
        const float* src;
        unsigned short* dst;
        if (row < N_USER) {
            src = user_emb + (size_t)user_ids[row] * D;
            dst = T_user + (size_t)row * 128;
        } else {
            int r = row - N_USER;
            src = item_x + (size_t)r * D;
            dst = T_item + (size_t)r * 128;
        }
        const float4 v = *reinterpret_cast<const float4*>(src + c);
        ushortx4 o;
        o.x = f2bf(v.x); o.y = f2bf(v.y); o.z = f2bf(v.z); o.w = f2bf(v.w);
        *reinterpret_cast<ushortx4*>(dst + c) = o;
    } else if (b < PACKA_BLOCKS + CNT_BLOCKS) {
        for (int i = tid; i < NBKT; i += 256) bcnt[i] = 0;
        __syncthreads();
        int e0 = (b - PACKA_BLOCKS) * 4096;
#pragma unroll
        for (int j = 0; j < 16; ++j) {
            int e = e0 + j * 256 + tid;
            if (e < NE2) {
                int d = (e < N_EDGE) ? edge_ui[N_EDGE + e]
                                     : (N_ITEM + edge_iu[N_EDGE + (e - N_EDGE)]);
                atomicAdd(&bcnt[d >> BKT_SH], 1);
            }
        }
        __syncthreads();
        for (int i = tid; i < NBKT; i += 256)
            if (bcnt[i]) atomicAdd(&gcnt[i], bcnt[i]);
    } else {
        int id = (b - PACKA_BLOCKS - CNT_BLOCKS) * 256 + tid;   // [0, 8192)
        const float *Wl, *Wr;
        unsigned short* Wf;
        if (id < 4096) { Wl = Wl_ui; Wr = Wr_ui; Wf = WfragUI; }
        else { id -= 4096; Wl = Wl_iu; Wr = Wr_iu; Wf = WfragIU; }
        int lane = id & 63;
        int c    = (id >> 6) & 7;
        int ks   = id >> 9;
        int col  = c * 16 + (lane & 15);
        int k0   = ks * 32 + (lane >> 4) * 8;
        ushortx8 o;
#pragma unroll
        for (int i = 0; i < 8; ++i) {
            int k = k0 + i;
            float f = (k < D) ? Wl[(size_t)k * D + col] : Wr[(size_t)(k - D) * D + col];
            o[i] = f2bf(f);
        }
        *reinterpret_cast<ushortx8*>(Wf + (size_t)id * 8) = o;
    }
}

// ---------------------------------------------------------------------------
// Scan 196 bucket counts -> bucket bases; init bucket cursors.
// ---------------------------------------------------------------------------
__global__ __launch_bounds__(256) void bucketscan_kernel(
    const int* __restrict__ gcnt, int* __restrict__ bbase, int* __restrict__ bcur)
{
    __shared__ int s[256];
    int tid = threadIdx.x;
    int v = (tid < NBKT) ? gcnt[tid] : 0;
    s[tid] = v;
    __syncthreads();
    for (int d = 1; d < 256; d <<= 1) {
        int t = (tid >= d) ? s[tid - d] : 0;
        __syncthreads();
        s[tid] += t;
        __syncthreads();
    }
    if (tid < NBKT) {
        int base = s[tid] - v;     // exclusive
        bbase[tid] = base;
        bcur[tid]  = base;
    }
    if (tid == NBKT - 1) bbase[NBKT] = s[tid];
}

// ---------------------------------------------------------------------------
// Scatter records into bucket-segmented array. Record = src16 | dstlow9<<16.
// Rank captured from the pass-1 count atomic; pass 2 reserves one chunk per
// (block,bucket); final writes are atomic-free: pos = chunk base + rank.
// ---------------------------------------------------------------------------
#define B2_BLOCKS 196   // ceil(NE2 / 8192)

__global__ __launch_bounds__(1024) void scatter_records_kernel(
    const int* __restrict__ edge_ui, const int* __restrict__ edge_iu,
    int* __restrict__ bcur, unsigned int* __restrict__ records)
{
    __shared__ int bcnt[NBKT];
    __shared__ int bpos[NBKT];
    const int tid = threadIdx.x;
    for (int i = tid; i < NBKT; i += 1024) bcnt[i] = 0;
    __syncthreads();

    const int e0 = blockIdx.x * 8192;
    unsigned int rec[8];
    int bkt[8], rnk[8];
#pragma unroll
    for (int j = 0; j < 8; ++j) {
        int e = e0 + j * 1024 + tid;
        bkt[j] = -1;
        if (e < NE2) {
            int s, d;
            if (e < N_EDGE) { s = edge_ui[e]; d = edge_ui[N_EDGE + e]; }
            else { int f = e - N_EDGE; s = edge_iu[f]; d = N_ITEM + edge_iu[N_EDGE + f]; }
            bkt[j] = d >> BKT_SH;
            rec[j] = (unsigned int)s | ((unsigned int)(d & 511) << 16);
            rnk[j] = atomicAdd(&bcnt[bkt[j]], 1);
        }
    }
    __syncthreads();
    for (int i = tid; i < NBKT; i += 1024) {
        int c = bcnt[i];
        bpos[i] = c ? atomicAdd(&bcur[i], c) : 0;
    }
    __syncthreads();
#pragma unroll
    for (int j = 0; j < 8; ++j) {
        if (bkt[j] >= 0) records[bpos[bkt[j]] + rnk[j]] = rec[j];
    }
}

// ---------------------------------------------------------------------------
// Per-bucket CSR build: LDS counting-sort by dst within the bucket; emits off[].
// ---------------------------------------------------------------------------
__global__ __launch_bounds__(1024) void csr_build_kernel(
    const unsigned int* __restrict__ records, const int* __restrict__ bbase,
    unsigned short* __restrict__ csr, int* __restrict__ off)
{
    __shared__ int dcnt[512];
    __shared__ int sa[512], sb[512];
    __shared__ int dcur[512];
    __shared__ unsigned short stage[CAP];

    const int b    = blockIdx.x;
    const int tid  = threadIdx.x;
    const int base = bbase[b];
    const int nb   = bbase[b + 1] - base;

    if (tid < 512) dcnt[tid] = 0;
    __syncthreads();

    for (int i = tid; i < nb; i += 1024)
        atomicAdd(&dcnt[records[base + i] >> 16], 1);
    __syncthreads();

    int* pa = sa; int* pb = sb;
    if (tid < 512) pa[tid] = dcnt[tid];
    __syncthreads();
    for (int d = 1; d < 512; d <<= 1) {
        if (tid < 512) pb[tid] = pa[tid] + ((tid >= d) ? pa[tid - d] : 0);
        __syncthreads();
        int* t = pa; pa = pb; pb = t;
    }
    if (tid < 512) {
        int excl = pa[tid] - dcnt[tid];
        dcur[tid] = excl;
        int dst = b * 512 + tid;
        if (dst < NTOT) off[dst] = base + excl;
    }
    if (b == NBKT - 1 && tid == 0) off[NTOT] = NE2;
    __syncthreads();

    if (nb <= CAP) {
        for (int i = tid; i < nb; i += 1024) {
            unsigned int r = records[base + i];
            int p = atomicAdd(&dcur[r >> 16], 1);
            stage[p] = (unsigned short)r;
        }
        __syncthreads();
        for (int i = tid; i < nb; i += 1024) csr[base + i] = stage[i];
    } else {
        for (int i = tid; i < nb; i += 1024) {
            unsigned int r = records[base + i];
            int p = atomicAdd(&dcur[r >> 16], 1);
            csr[base + p] = (unsigned short)r;
        }
    }
}

// ---------------------------------------------------------------------------
// FUSED aggregate + MFMA finish, v2 (wave-per-row aggregation).
// Block = 1024 thr = 16 waves, owns 64 output rows of one side.
//  phase 1: wave w aggregates rows {4w..4w+3}: one wave per row (agg2's
//           structure: lane owns dims [2l,2l+1], 4 independent gathers in
//           flight), mean -> LDS head tile hd[64][136] (bf16 pairs).
//  phase 2: 16 waves = 4 row-groups x 4 col-groups; each wave 16 MFMA
//           (8 k-steps x 2 col-blocks); A head from LDS, tail from Ts (self
//           features); out = A @ Wfrag + bias -> fp32 d_out.
// ---------------------------------------------------------------------------
#define NB_FIN 782   // ceil(50000/64)

__global__ __launch_bounds__(1024, 8) void aggfin2_kernel(
    const unsigned short* __restrict__ T_user, const unsigned short* __restrict__ T_item,
    const int* __restrict__ off, const unsigned short* __restrict__ csr,
    const unsigned short* __restrict__ WfragUI, const unsigned short* __restrict__ WfragIU,
    const float* __restrict__ b_ui, const float* __restrict__ b_iu,
    float* out_item, float* out_user)
{
    __shared__ unsigned short hd[64][136];   // head tile, padded stride

    const int b = blockIdx.x;
    const unsigned short *Tg, *Ts, *Wfrag;
    const float* bias;
    float* outp;
    int rowBase, dstOfs;
    if (b < NB_FIN) {
        // item side: aggregate USER features, self = ITEM features
        Tg = T_user; Ts = T_item; Wfrag = WfragUI; bias = b_ui;
        outp = out_item; rowBase = b * 64; dstOfs = 0;
    } else {
        // user side: aggregate ITEM features, self = USER features
        Tg = T_item; Ts = T_user; Wfrag = WfragIU; bias = b_iu;
        outp = out_user; rowBase = (b - NB_FIN) * 64; dstOfs = N_ITEM;
    }

    const int tid  = threadIdx.x;
    const int wave = tid >> 6;       // 0..15
    const int lane = tid & 63;

    // ---- phase 1: aggregation, one wave per row ----
    const int co = lane * 2;
#pragma unroll
    for (int rr = 0; rr < 4; ++rr) {
        const int lrow = wave * 4 + rr;
        const int row  = rowBase + lrow;
        float ax = 0.f, ay = 0.f;
        int deg = 0;
        if (row < 50000) {
            const int dr = dstOfs + row;
            const int o0 = off[dr], o1 = off[dr + 1];
            deg = o1 - o0;
            int i = o0;
            for (; i + 3 < o1; i += 4) {
                int s0 = csr[i], s1 = csr[i + 1], s2 = csr[i + 2], s3 = csr[i + 3];
                unsigned int w0 = *reinterpret_cast<const unsigned int*>(Tg + (size_t)s0 * 128 + co);
                unsigned int w1 = *reinterpret_cast<const unsigned int*>(Tg + (size_t)s1 * 128 + co);
                unsigned int w2 = *reinterpret_cast<const unsigned int*>(Tg + (size_t)s2 * 128 + co);
                unsigned int w3 = *reinterpret_cast<const unsigned int*>(Tg + (size_t)s3 * 128 + co);
                ax += bf2f((unsigned short)w0) + bf2f((unsigned short)w1)
                    + bf2f((unsigned short)w2) + bf2f((unsigned short)w3);
                ay += bf2f((unsigned short)(w0 >> 16)) + bf2f((unsigned short)(w1 >> 16))
                    + bf2f((unsigned short)(w2 >> 16)) + bf2f((unsigned short)(w3 >> 16));
            }
            for (; i < o1; ++i) {
                int s = csr[i];
                unsigned int w = *reinterpret_cast<const unsigned int*>(Tg + (size_t)s * 128 + co);
                ax += bf2f((unsigned short)w);
                ay += bf2f((unsigned short)(w >> 16));
            }
        }
        float sc = (deg > 0) ? 1.0f / (float)deg : 0.0f;
        unsigned int outw = (unsigned int)f2bf(ax * sc) | ((unsigned int)f2bf(ay * sc) << 16);
        *reinterpret_cast<unsigned int*>(&hd[lrow][co]) = outw;
    }
    __syncthreads();

    // ---- phase 2: MFMA (wave = row-group rg x col-group cg) ----
    const int rg = wave >> 2;
    const int cg = wave & 3;
    const int kg = lane >> 4;
    const int lrow2  = rg * 16 + (lane & 15);
    const int arow   = rowBase + lrow2;
    const int arow_c = (arow < 50000) ? arow : 49999;
    const unsigned short* tail_ptr = Ts + (size_t)arow_c * 128 + kg * 8;   // SELF features
    const unsigned short* hrow = &hd[lrow2][kg * 8];

    f32x4 acc0 = (f32x4){0.f, 0.f, 0.f, 0.f};
    f32x4 acc1 = (f32x4){0.f, 0.f, 0.f, 0.f};

#pragma unroll
    for (int ks = 0; ks < 8; ++ks) {
        bf16x8 a;
        if (ks < 4) a = *reinterpret_cast<const bf16x8*>(hrow + ks * 32);           // agg (Wl)
        else        a = *reinterpret_cast<const bf16x8*>(tail_ptr + (ks - 4) * 32); // self (Wr)
        const unsigned short* bptr = Wfrag + ((size_t)(ks * 8 + cg * 2) * 64 + lane) * 8;
        bf16x8 b0 = *reinterpret_cast<const bf16x8*>(bptr);
        bf16x8 b1 = *reinterpret_cast<const bf16x8*>(bptr + 512);
        acc0 = __builtin_amdgcn_mfma_f32_16x16x32_bf16(a, b0, acc0, 0, 0, 0);
        acc1 = __builtin_amdgcn_mfma_f32_16x16x32_bf16(a, b1, acc1, 0, 0, 0);
    }

    const int orow0 = rowBase + rg * 16 + kg * 4;
    const int ocol  = cg * 32 + (lane & 15);
    const float bv0 = bias[ocol];
    const float bv1 = bias[ocol + 16];
#pragma unroll
    for (int r = 0; r < 4; ++r) {
        int row = orow0 + r;
        if (row < 50000) {
            outp[(size_t)row * 128 + ocol]      = acc0[r] + bv0;
            outp[(size_t)row * 128 + ocol + 16] = acc1[r] + bv1;
        }
    }
}

// ---------------------------------------------------------------------------
extern "C" void kernel_launch(void* const* d_in, const int* in_sizes, int n_in,
                              void* d_out, int out_size, void* d_ws, size_t ws_size,
                              hipStream_t stream) {
    const int*   user_ids = (const int*)d_in[0];
    const float* item_x   = (const float*)d_in[1];
    const int*   edge_ui  = (const int*)d_in[2];
    const int*   edge_iu  = (const int*)d_in[3];
    const float* user_emb = (const float*)d_in[4];
    const float* W_l_ui   = (const float*)d_in[5];
    const float* W_r_ui   = (const float*)d_in[6];
    const float* b_ui     = (const float*)d_in[7];
    const float* W_l_iu   = (const float*)d_in[8];
    const float* W_r_iu   = (const float*)d_in[9];
    const float* b_iu     = (const float*)d_in[10];

    float* out_user = (float*)d_out;
    float* out_item = out_user + (size_t)N_USER * D;

    // Workspace (16B-aligned blocks first)
    unsigned short* WfragUI = (unsigned short*)d_ws;            // 32768 u16
    unsigned short* WfragIU = WfragUI + 32768;                  // 32768 u16
    unsigned short* T_user  = WfragIU + 32768;                  // 50000*128 u16 (12.8MB)
    unsigned short* T_item  = T_user + (size_t)N_USER * 128;    // 12.8MB
    unsigned int*   records = (unsigned int*)(T_item + (size_t)N_ITEM * 128);  // NE2 (6.4MB)
    unsigned short* csr     = (unsigned short*)(records + NE2); // NE2 (3.2MB)
    int* gcnt  = (int*)(csr + NE2);                             // NBKT
    int* bbase = gcnt + NBKT;                                   // NBKT+1
    int* bcur  = bbase + NBKT + 1;                              // NBKT
    int* off   = bcur + NBKT;                                   // NTOT+1

    hipMemsetAsync(gcnt, 0, NBKT * sizeof(int), stream);

    prep2_kernel<<<PACKA_BLOCKS + CNT_BLOCKS + PACKW_BLOCKS, 256, 0, stream>>>(
        user_emb, user_ids, item_x, edge_ui, edge_iu,
        W_l_ui, W_r_ui, W_l_iu, W_r_iu,
        T_user, T_item, gcnt, WfragUI, WfragIU);

    bucketscan_kernel<<<1, 256, 0, stream>>>(gcnt, bbase, bcur);
    scatter_records_kernel<<<B2_BLOCKS, 1024, 0, stream>>>(edge_ui, edge_iu, bcur, records);
    csr_build_kernel<<<NBKT, 1024, 0, stream>>>(records, bbase, csr, off);

    aggfin2_kernel<<<2 * NB_FIN, 1024, 0, stream>>>(
        T_user, T_item, off, csr, WfragUI, WfragIU, b_ui, b_iu, out_item, out_user);
}